// Round 12
// baseline (1266.856 us; speedup 1.0000x reference)
//
#include <hip/hip_runtime.h>
#include <hip/hip_bf16.h>

#define BB 64
#define TT 512
#define HH 256
#define EE 128
#define VV 32000
#define SS 128
#define LL 16

typedef __attribute__((ext_vector_type(8))) short bf16x8;
typedef __attribute__((ext_vector_type(4))) float f32x4;

static __device__ __forceinline__ unsigned short f2bf(float x) {
    unsigned int u = __float_as_uint(x);
    unsigned int r = (u + 0x7fffu + ((u >> 16) & 1u)) >> 16;
    return (unsigned short)r;
}

// tanh(x) = 1 - 2/(exp2(x*2*log2e)+1)
static __device__ __forceinline__ float ftanh(float x) {
    float y = __builtin_amdgcn_exp2f(x * 2.885390082f);
    return 1.f - 2.f * __builtin_amdgcn_rcpf(y + 1.f);
}

// ================= K1: {hW, prep_b, embed, slot-firstidx} by blockIdx =================
__global__ __launch_bounds__(256) void k_pre(const float* __restrict__ last_hidden,
                                             const float* __restrict__ attn_W,
                                             const float* __restrict__ attn_b,
                                             const int* __restrict__ z_tm1,
                                             const float* __restrict__ emb_W,
                                             const float* __restrict__ ctrl_W,
                                             const float* __restrict__ ctrl_b,
                                             const int* __restrict__ slot,
                                             float* __restrict__ hW,
                                             float* __restrict__ embed,
                                             unsigned short* __restrict__ Bs,
                                             int* __restrict__ fidx) {
    __shared__ float sh[HH];
    __shared__ int shi[256];
    int blk = blockIdx.x;
    int tid = threadIdx.x;
    if (blk < 64) {
        int b = blk, h = tid;
        sh[h] = last_hidden[b * HH + h];
        __syncthreads();
        const float4* wrow = (const float4*)(attn_W + (size_t)h * (2 * HH));
        float a0 = 0.f, a1 = 0.f, a2 = 0.f, a3 = 0.f;
        for (int k4 = 0; k4 < HH / 4; k4 += 4) {
            float4 w0 = wrow[k4], w1 = wrow[k4+1], w2 = wrow[k4+2], w3 = wrow[k4+3];
            a0 += sh[k4*4+ 0]*w0.x + sh[k4*4+ 1]*w0.y + sh[k4*4+ 2]*w0.z + sh[k4*4+ 3]*w0.w;
            a1 += sh[k4*4+ 4]*w1.x + sh[k4*4+ 5]*w1.y + sh[k4*4+ 6]*w1.z + sh[k4*4+ 7]*w1.w;
            a2 += sh[k4*4+ 8]*w2.x + sh[k4*4+ 9]*w2.y + sh[k4*4+10]*w2.z + sh[k4*4+11]*w2.w;
            a3 += sh[k4*4+12]*w3.x + sh[k4*4+13]*w3.y + sh[k4*4+14]*w3.z + sh[k4*4+15]*w3.w;
        }
        hW[b * HH + h] = attn_b[h] + ((a0 + a1) + (a2 + a3));
    } else if (blk < 96) {
        // Bs layout: [kstep 0..7][tile 0..15][lane 0..63][8 bf16]
        int idx = (blk - 64) * 256 + tid;  // 8192 total
        int lane = idx & 63;
        int gt = (idx >> 6) & 15;
        int ks = idx >> 10;
        int col = gt * 16 + (lane & 15);
        int k0 = ks * 32 + (lane >> 4) * 8;
        const float* src = attn_W + (size_t)col * (2 * HH) + HH + k0;
        unsigned int p0 = f2bf(src[0]) | ((unsigned int)f2bf(src[1]) << 16);
        unsigned int p1 = f2bf(src[2]) | ((unsigned int)f2bf(src[3]) << 16);
        unsigned int p2 = f2bf(src[4]) | ((unsigned int)f2bf(src[5]) << 16);
        unsigned int p3 = f2bf(src[6]) | ((unsigned int)f2bf(src[7]) << 16);
        *(uint4*)(Bs + (size_t)idx * 8) = make_uint4(p0, p1, p2, p3);
    } else if (blk < 160) {
        int b = blk - 96;
        if (tid < EE) sh[tid] = emb_W[(size_t)z_tm1[b] * EE + tid];
        __syncthreads();
        if (tid < EE) {
            const float4* wrow = (const float4*)(ctrl_W + (size_t)tid * EE);
            float a0 = 0.f, a1 = 0.f;
            for (int k4 = 0; k4 < EE / 4; k4 += 2) {
                float4 w0 = wrow[k4], w1 = wrow[k4+1];
                a0 += sh[k4*4+0]*w0.x + sh[k4*4+1]*w0.y + sh[k4*4+2]*w0.z + sh[k4*4+3]*w0.w;
                a1 += sh[k4*4+4]*w1.x + sh[k4*4+5]*w1.y + sh[k4*4+6]*w1.z + sh[k4*4+7]*w1.w;
            }
            embed[b * EE + tid] = ctrl_b[tid] + sh[tid] + a0 + a1;
        }
    } else {
        // blocks 160..167: firstidx[l][s]
        int lblk = (blk - 160) * 2;
        shi[tid] = slot[lblk * SS + tid];
        __syncthreads();
        int lrow = tid >> 7, s = tid & 127;
        int c = shi[lrow * 128 + s];
        int fi = s;
        for (int s2 = 0; s2 < 128; ++s2) {
            if (shi[lrow * 128 + s2] == c) { fi = s2; break; }
        }
        fidx[(lblk + lrow) * SS + s] = fi;
    }
}

// ================= K2: fused scores+context (flash-style), block=(c,b) =================
// Writes partial[c][b][h] = sum_t exp(s_t - m_c) enc[t][h], mArr[b*16+c]=m_c, dArr=d_c.
__device__ __forceinline__ void sctx_body(int c, int b, int tid,
                                          const float* __restrict__ enc,
                                          const unsigned short* __restrict__ Bs,
                                          const float* __restrict__ attn_v,
                                          const float* __restrict__ hW,
                                          float* __restrict__ partial,
                                          float* __restrict__ mArr,
                                          float* __restrict__ dArr,
                                          unsigned char* Abuf, float* scpart,
                                          float* wloc, float* part) {
    int t0 = c * 32;

    // stage 32 rows (t0..t0+31) of fixed b: f32 -> bf16, XOR-swizzled
#pragma unroll
    for (int it = 0; it < 4; ++it) {
        int ci = tid + it * 256;
        int row = ci >> 5;
        int kc = ci & 31;
        const float* src = enc + ((size_t)(t0 + row) * BB + b) * HH + kc * 8;
        float4 f0 = *(const float4*)src;
        float4 f1 = *(const float4*)(src + 4);
        unsigned int p0 = f2bf(f0.x) | ((unsigned int)f2bf(f0.y) << 16);
        unsigned int p1 = f2bf(f0.z) | ((unsigned int)f2bf(f0.w) << 16);
        unsigned int p2 = f2bf(f1.x) | ((unsigned int)f2bf(f1.y) << 16);
        unsigned int p3 = f2bf(f1.z) | ((unsigned int)f2bf(f1.w) << 16);
        int addr = (row * 512 + kc * 16) ^ ((row & 7) << 4);
        *(uint4*)(Abuf + addr) = make_uint4(p0, p1, p2, p3);
    }
    __syncthreads();

    int wv = tid >> 6, lane = tid & 63;
    int lrow = lane & 15, q = lane >> 4;

    f32x4 acc[2][4];
#pragma unroll
    for (int rt = 0; rt < 2; ++rt)
#pragma unroll
        for (int ct = 0; ct < 4; ++ct) acc[rt][ct] = (f32x4){0.f, 0.f, 0.f, 0.f};

    const bf16x8* BsV = (const bf16x8*)Bs;
    for (int ks = 0; ks < 8; ++ks) {
        bf16x8 bfr[4];
        const bf16x8* bsrc = BsV + ((size_t)(ks * 16 + wv * 4) * 64 + lane);
#pragma unroll
        for (int ct = 0; ct < 4; ++ct) bfr[ct] = bsrc[ct * 64];
        bf16x8 afr[2];
#pragma unroll
        for (int rt = 0; rt < 2; ++rt) {
            int arow = rt * 16 + lrow;
            int abyte = (arow * 512 + ks * 64 + q * 16) ^ ((arow & 7) << 4);
            afr[rt] = *(const bf16x8*)(Abuf + abyte);
        }
#pragma unroll
        for (int rt = 0; rt < 2; ++rt)
#pragma unroll
            for (int ct = 0; ct < 4; ++ct)
                acc[rt][ct] = __builtin_amdgcn_mfma_f32_16x16x32_bf16(afr[rt], bfr[ct], acc[rt][ct], 0, 0, 0);
    }

    // epilogue: s_t = sum_h v[h] tanh(E + hW[b,h]); hW uniform across rows now
    float vvv[4], hwv[4];
#pragma unroll
    for (int ct = 0; ct < 4; ++ct) {
        int col = wv * 64 + ct * 16 + lrow;
        vvv[ct] = attn_v[col];
        hwv[ct] = hW[(size_t)b * HH + col];
    }
#pragma unroll
    for (int rt = 0; rt < 2; ++rt) {
        float ps[4];
#pragma unroll
        for (int r = 0; r < 4; ++r) {
            float s = 0.f;
#pragma unroll
            for (int ct = 0; ct < 4; ++ct)
                s += vvv[ct] * ftanh(acc[rt][ct][r] + hwv[ct]);
#pragma unroll
            for (int off = 1; off < 16; off <<= 1) s += __shfl_xor(s, off, 64);
            ps[r] = s;
        }
        if (lrow == 0) {
#pragma unroll
            for (int r = 0; r < 4; ++r) scpart[wv * 32 + rt * 16 + q * 4 + r] = ps[r];
        }
    }
    __syncthreads();

    // wave 0: local softmax stats over the 32 rows
    if (tid < 64) {
        float s = (tid < 32)
            ? ((scpart[tid] + scpart[32 + tid]) + (scpart[64 + tid] + scpart[96 + tid]))
            : -3.0e38f;
        float mx = s;
#pragma unroll
        for (int off = 32; off; off >>= 1) mx = fmaxf(mx, __shfl_xor(mx, off, 64));
        float e = (tid < 32) ? expf(s - mx) : 0.f;
        float d = e;
#pragma unroll
        for (int off = 32; off; off >>= 1) d += __shfl_xor(d, off, 64);
        if (tid < 32) wloc[tid] = e;
        if (tid == 0) { mArr[b * 16 + c] = mx; dArr[b * 16 + c] = d; }
    }
    __syncthreads();

    // ctx accumulate from global (L2-hot): group g handles t = t0+g*8..+7
    {
        int h4 = tid & 63, g = tid >> 6;
        f32x4 c4 = {0.f, 0.f, 0.f, 0.f};
        f32x4 d4 = {0.f, 0.f, 0.f, 0.f};
        const f32x4* enc4 = (const f32x4*)enc;
        size_t base = ((size_t)(t0 + g * 8) * BB + b) * 64 + h4;
#pragma unroll
        for (int i = 0; i < 8; i += 2) {
            float w0 = wloc[g * 8 + i], w1 = wloc[g * 8 + i + 1];
            f32x4 v0 = enc4[base + (size_t)i * BB * 64];
            f32x4 v1 = enc4[base + (size_t)(i + 1) * BB * 64];
            c4.x += w0 * v0.x; c4.y += w0 * v0.y; c4.z += w0 * v0.z; c4.w += w0 * v0.w;
            d4.x += w1 * v1.x; d4.y += w1 * v1.y; d4.z += w1 * v1.z; d4.w += w1 * v1.w;
        }
        c4.x += d4.x; c4.y += d4.y; c4.z += d4.z; c4.w += d4.w;
        *(f32x4*)&part[g * 256 + h4 * 4] = c4;
    }
    __syncthreads();
    if (tid < 64) {
        f32x4 a0 = *(const f32x4*)&part[0 * 256 + tid * 4];
        f32x4 a1 = *(const f32x4*)&part[1 * 256 + tid * 4];
        f32x4 a2 = *(const f32x4*)&part[2 * 256 + tid * 4];
        f32x4 a3 = *(const f32x4*)&part[3 * 256 + tid * 4];
        f32x4 t4;
        t4.x = (a0.x + a1.x) + (a2.x + a3.x);
        t4.y = (a0.y + a1.y) + (a2.y + a3.y);
        t4.z = (a0.z + a1.z) + (a2.z + a3.z);
        t4.w = (a0.w + a1.w) + (a2.w + a3.w);
        *(f32x4*)&partial[((size_t)c * BB + b) * HH + tid * 4] = t4;
    }
}

__global__ __launch_bounds__(256) void k_sctx(const float* __restrict__ enc,
                                              const unsigned short* __restrict__ Bs,
                                              const float* __restrict__ attn_v,
                                              const float* __restrict__ hW,
                                              float* __restrict__ partial,
                                              float* __restrict__ mArr,
                                              float* __restrict__ dArr) {
    __shared__ uint4 AbufV[1024];
    __shared__ float scpart[128];
    __shared__ float wloc[32];
    __shared__ __align__(16) float part[1024];
    sctx_body(blockIdx.x, blockIdx.y, threadIdx.x, enc, Bs, attn_v, hW,
              partial, mArr, dArr, (unsigned char*)AbufV, scpart, wloc, part);
}

// INSTRUMENT
__global__ __launch_bounds__(256) void k_sctx_x16(const float* __restrict__ enc,
                                                  const unsigned short* __restrict__ Bs,
                                                  const float* __restrict__ attn_v,
                                                  const float* __restrict__ hW,
                                                  float* __restrict__ partial,
                                                  float* __restrict__ mArr,
                                                  float* __restrict__ dArr) {
    __shared__ uint4 AbufV[1024];
    __shared__ float scpart[128];
    __shared__ float wloc[32];
    __shared__ __align__(16) float part[1024];
    for (int rep = 0; rep < 16; ++rep) {
        __syncthreads();
        sctx_body(blockIdx.x, blockIdx.y, threadIdx.x, enc, Bs, attn_v, hW,
                  partial, mArr, dArr, (unsigned char*)AbufV, scpart, wloc, part);
    }
}

// ================= K3: combine + hidden + gen + probas-stats =================
// smem carve (floats): part[1024]@0, fin[640]@1024, hid[256]@1664, genl[128]@1920,
//   red[128]@2048, genacc[2048]@2176, fidxL(int)[2048]@4224, ldm[16]@6272, ldd[16]@6288.
__device__ __forceinline__ void ffnn_body(int b, int tid,
                                          const float* __restrict__ partial,
                                          const float* __restrict__ mArr,
                                          const float* __restrict__ dArr,
                                          const float* __restrict__ embed,
                                          const float* __restrict__ last_hidden,
                                          const float* __restrict__ Whid,
                                          const float* __restrict__ bhid,
                                          const float* __restrict__ Wout,
                                          const float* __restrict__ bout,
                                          const int* __restrict__ fidx,
                                          float* __restrict__ out_hidden,
                                          float* __restrict__ gen,
                                          float* __restrict__ pvals,
                                          float* __restrict__ pbase,
                                          float* smem) {
    float* part   = smem;
    float* fin    = smem + 1024;
    float* hid    = smem + 1664;
    float* genl   = smem + 1920;
    float* red    = smem + 2048;
    float* genacc = smem + 2176;
    int*   fidxL  = (int*)(smem + 4224);
    float* ldm    = smem + 6272;
    float* ldd    = smem + 6288;

    int tid10 = tid;
    int lane = tid & 63, wv = tid >> 6;

    fidxL[tid10] = fidx[tid10];
    fidxL[tid10 + 1024] = fidx[tid10 + 1024];
    genacc[tid10] = 0.f;
    genacc[tid10 + 1024] = 0.f;
    if (tid < 16) { ldm[tid] = mArr[b * 16 + tid]; ldd[tid] = dArr[b * 16 + tid]; }
    __syncthreads();

    // softmax combine factors (redundant per thread, 16-wide)
    float M = ldm[0];
#pragma unroll
    for (int cc = 1; cc < 16; ++cc) M = fmaxf(M, ldm[cc]);
    float den = 0.f;
#pragma unroll
    for (int cc = 0; cc < 16; ++cc) den += expf(ldm[cc] - M) * ldd[cc];
    float invden = 1.f / den;

    // phase A: scaled sum of 16 partials
    {
        int h = tid & 255, pc = tid >> 8;
        float a0 = 0.f, a1 = 0.f;
#pragma unroll
        for (int j = 0; j < 4; j += 2) {
            int c0 = pc * 4 + j, c1 = pc * 4 + j + 1;
            a0 += expf(ldm[c0] - M) * partial[((size_t)c0 * BB + b) * HH + h];
            a1 += expf(ldm[c1] - M) * partial[((size_t)c1 * BB + b) * HH + h];
        }
        part[pc * 256 + h] = a0 + a1;
    }
    __syncthreads();
    if (tid < 256) fin[EE + tid] = ((part[tid] + part[256 + tid]) + (part[512 + tid] + part[768 + tid])) * invden;
    else if (tid < 384) fin[tid - 256] = embed[b * EE + (tid - 256)];
    else if (tid < 640) fin[EE + HH + (tid - 384)] = last_hidden[b * HH + (tid - 384)];
    __syncthreads();

    // phase B: hidden (4-way chain break)
    {
        int o = tid & 255, kh = tid >> 8;
        const f32x4* wrow = (const f32x4*)(Whid + (size_t)o * (2 * HH + EE)) + kh * 40;
        const float* fb = fin + kh * 160;
        float a0 = 0.f, a1 = 0.f, a2 = 0.f, a3 = 0.f;
#pragma unroll
        for (int k4 = 0; k4 < 40; k4 += 4) {
            f32x4 w0 = wrow[k4], w1 = wrow[k4+1], w2 = wrow[k4+2], w3 = wrow[k4+3];
            a0 += fb[k4*4+ 0]*w0.x + fb[k4*4+ 1]*w0.y + fb[k4*4+ 2]*w0.z + fb[k4*4+ 3]*w0.w;
            a1 += fb[k4*4+ 4]*w1.x + fb[k4*4+ 5]*w1.y + fb[k4*4+ 6]*w1.z + fb[k4*4+ 7]*w1.w;
            a2 += fb[k4*4+ 8]*w2.x + fb[k4*4+ 9]*w2.y + fb[k4*4+10]*w2.z + fb[k4*4+11]*w2.w;
            a3 += fb[k4*4+12]*w3.x + fb[k4*4+13]*w3.y + fb[k4*4+14]*w3.z + fb[k4*4+15]*w3.w;
        }
        part[kh * 256 + o] = (a0 + a1) + (a2 + a3);
    }
    __syncthreads();
    if (tid < HH) {
        float hv = fmaxf((part[tid] + part[256 + tid]) + (part[512 + tid] + part[768 + tid]) + bhid[tid], 0.f);
        hid[tid] = hv;
        out_hidden[(size_t)b * HH + tid] = hv;
    }
    __syncthreads();

    // phase C: gen
    {
        int o = tid & 127, q8 = tid >> 7;
        const f32x4* wrow = (const f32x4*)(Wout + (size_t)o * HH) + q8 * 8;
        const float* hb = hid + q8 * 32;
        float a0 = 0.f, a1 = 0.f;
#pragma unroll
        for (int k4 = 0; k4 < 8; k4 += 2) {
            f32x4 w0 = wrow[k4], w1 = wrow[k4+1];
            a0 += hb[k4*4+0]*w0.x + hb[k4*4+1]*w0.y + hb[k4*4+2]*w0.z + hb[k4*4+3]*w0.w;
            a1 += hb[k4*4+4]*w1.x + hb[k4*4+5]*w1.y + hb[k4*4+6]*w1.z + hb[k4*4+7]*w1.w;
        }
        part[q8 * 128 + o] = a0 + a1;
    }
    __syncthreads();
    if (tid < SS) {
        float gv = bout[tid];
#pragma unroll
        for (int j = 0; j < 8; ++j) gv += part[j * 128 + tid];
        gv = fmaxf(gv, 0.f);
        genl[tid] = gv;
        gen[(size_t)b * SS + tid] = gv;
    }
    __syncthreads();

    // phase D: probas stats via firstidx + LDS atomic merge
    {
        int sA = tid & 127, lA = tid >> 7, lB = lA + 8;
        int fiA = fidxL[lA * SS + sA];
        int fiB = fidxL[lB * SS + sA];
        bool fA = (fiA == sA), fB = (fiB == sA);
        float gs = genl[sA];
        atomicAdd(&genacc[lA * SS + fiA], gs);
        atomicAdd(&genacc[lB * SS + fiB], gs);
        __syncthreads();
        float mgA = -0.01f + genacc[lA * SS + sA];
        float mgB = -0.01f + genacc[lB * SS + sA];
        float mA = fA ? mgA : -3.0e38f;
        float mB = fB ? mgB : -3.0e38f;
#pragma unroll
        for (int off = 32; off; off >>= 1) {
            mA = fmaxf(mA, __shfl_xor(mA, off, 64));
            mB = fmaxf(mB, __shfl_xor(mB, off, 64));
        }
        if (lane == 0) { red[wv] = mA; red[16 + wv] = mB; }
        __syncthreads();
        float MA = fmaxf(red[2 * lA], red[2 * lA + 1]);
        float MB = fmaxf(red[16 + 2 * lA], red[16 + 2 * lA + 1]);
        float eA = fA ? expf(mgA - MA) : 0.f;
        float eB = fB ? expf(mgB - MB) : 0.f;
        float cA = fA ? 1.f : 0.f, cB = fB ? 1.f : 0.f;
        float s1 = eA, s2v = cA, s3 = eB, s4 = cB;
#pragma unroll
        for (int off = 32; off; off >>= 1) {
            s1 += __shfl_xor(s1, off, 64);
            s2v += __shfl_xor(s2v, off, 64);
            s3 += __shfl_xor(s3, off, 64);
            s4 += __shfl_xor(s4, off, 64);
        }
        if (lane == 0) { red[32 + wv] = s1; red[48 + wv] = s2v; red[64 + wv] = s3; red[80 + wv] = s4; }
        __syncthreads();
        float sumA = red[32 + 2 * lA] + red[32 + 2 * lA + 1];
        float cntA = red[48 + 2 * lA] + red[48 + 2 * lA + 1];
        float sumB = red[64 + 2 * lA] + red[64 + 2 * lA + 1];
        float cntB = red[80 + 2 * lA] + red[80 + 2 * lA + 1];
        float baseA = expf(-0.01f - MA);
        float invA = 1.f / (((float)VV - cntA) * baseA + sumA);
        float baseB = expf(-0.01f - MB);
        float invB = 1.f / (((float)VV - cntB) * baseB + sumB);
        pvals[((size_t)b * LL + lA) * SS + sA] = fA ? eA * invA : -1.f;
        pvals[((size_t)b * LL + lB) * SS + sA] = fB ? eB * invB : -1.f;
        if (sA == 0) {
            pbase[b * LL + lA] = baseA * invA;
            pbase[b * LL + lB] = baseB * invB;
        }
    }
    __syncthreads();
}

__global__ __launch_bounds__(1024) void k_ffnn(const float* __restrict__ partial,
                                               const float* __restrict__ mArr,
                                               const float* __restrict__ dArr,
                                               const float* __restrict__ embed,
                                               const float* __restrict__ last_hidden,
                                               const float* __restrict__ Whid,
                                               const float* __restrict__ bhid,
                                               const float* __restrict__ Wout,
                                               const float* __restrict__ bout,
                                               const int* __restrict__ fidx,
                                               float* __restrict__ out_hidden,
                                               float* __restrict__ gen,
                                               float* __restrict__ pvals,
                                               float* __restrict__ pbase) {
    __shared__ __align__(16) float smem[6304];
    ffnn_body(blockIdx.x, threadIdx.x, partial, mArr, dArr, embed, last_hidden,
              Whid, bhid, Wout, bout, fidx, out_hidden, gen, pvals, pbase, smem);
}

// INSTRUMENT
__global__ __launch_bounds__(1024) void k_ffnn_x32(const float* __restrict__ partial,
                                                   const float* __restrict__ mArr,
                                                   const float* __restrict__ dArr,
                                                   const float* __restrict__ embed,
                                                   const float* __restrict__ last_hidden,
                                                   const float* __restrict__ Whid,
                                                   const float* __restrict__ bhid,
                                                   const float* __restrict__ Wout,
                                                   const float* __restrict__ bout,
                                                   const int* __restrict__ fidx,
                                                   float* __restrict__ out_hidden,
                                                   float* __restrict__ gen,
                                                   float* __restrict__ pvals,
                                                   float* __restrict__ pbase) {
    __shared__ __align__(16) float smem[6304];
    for (int rep = 0; rep < 32; ++rep) {
        __syncthreads();
        ffnn_body(blockIdx.x, threadIdx.x, partial, mArr, dArr, embed, last_hidden,
                  Whid, bhid, Wout, bout, fidx, out_hidden, gen, pvals, pbase, smem);
    }
}

// ================= K4: streaming fill + scatter, half-rows =================
__global__ __launch_bounds__(256) void k_fill(const int* __restrict__ slot,
                                              const float* __restrict__ pvals,
                                              const float* __restrict__ pbase,
                                              float* __restrict__ out) {
    int bx = blockIdx.x;
    int row = bx >> 1, half = bx & 1;
    int l = row >> 6, b = row & 63;
    int tid = threadIdx.x;
    __shared__ float pv[SS];
    __shared__ int cls[SS];
    if (tid < SS) {
        pv[tid] = pvals[((size_t)b * LL + l) * SS + tid];
        cls[tid] = slot[l * SS + tid];
    }
    float pb = pbase[b * LL + l];
    float* rowp = out + BB * HH + ((size_t)(l * BB + b)) * VV;
    float4 p4 = make_float4(pb, pb, pb, pb);
    float4* row4 = (float4*)rowp + half * (VV / 8);
#pragma unroll 4
    for (int idx = tid; idx < VV / 8; idx += 256) row4[idx] = p4;
    __syncthreads();
    if (tid < SS && pv[tid] >= 0.f) {
        int c = cls[tid];
        int lo = half * (VV / 2);
        if (c >= lo && c < lo + VV / 2) rowp[c] = pv[tid];
    }
}

extern "C" void kernel_launch(void* const* d_in, const int* in_sizes, int n_in,
                              void* d_out, int out_size, void* d_ws, size_t ws_size,
                              hipStream_t stream) {
    const float* u_enc       = (const float*)d_in[0];
    const float* last_hidden = (const float*)d_in[1];
    const int*   z_tm1       = (const int*)d_in[2];
    const int*   slot        = (const int*)d_in[3];
    const float* emb_W       = (const float*)d_in[4];
    const float* ctrl_W      = (const float*)d_in[5];
    const float* ctrl_b      = (const float*)d_in[6];
    const float* attn_W      = (const float*)d_in[7];
    const float* attn_b      = (const float*)d_in[8];
    const float* attn_v      = (const float*)d_in[9];
    const float* Whid        = (const float*)d_in[10];
    const float* bhid        = (const float*)d_in[11];
    const float* Wout        = (const float*)d_in[12];
    const float* bout        = (const float*)d_in[13];
    float* out = (float*)d_out;
    float* ws = (float*)d_ws;

    float* mArr    = ws;             // 1024
    float* dArr    = ws + 1024;      // 1024
    float* hW      = ws + 32768;     // 16384
    float* embed   = ws + 49152;     // 8192
    float* gen     = ws + 57344;     // 8192
    unsigned short* Bs = (unsigned short*)(ws + 65536);  // 65536 bf16
    float* pvals   = ws + 98304;     // 131072
    float* pbase   = ws + 229376;    // 1024
    float* partial = ws + 230400;    // 262144
    int*   fidx    = (int*)(ws + 492544);  // 2048 ints

    k_pre<<<168, 256, 0, stream>>>(last_hidden, attn_W, attn_b, z_tm1, emb_W, ctrl_W,
                                   ctrl_b, slot, hW, embed, Bs, fidx);
    dim3 gs(16, BB);
    k_sctx<<<gs, 256, 0, stream>>>(u_enc, Bs, attn_v, hW, partial, mArr, dArr);
    k_ffnn<<<BB, 1024, 0, stream>>>(partial, mArr, dArr, embed, last_hidden, Whid, bhid,
                                    Wout, bout, fidx, out, gen, pvals, pbase);
    k_fill<<<LL * BB * 2, 256, 0, stream>>>(slot, pvals, pbase, out);

    // ---- instruments (scratch-only, deterministic) ----
    if (ws_size >= ((size_t)64 << 20)) {
        float* partial2 = ws + 2097152;   // 262144
        float* mArr2    = ws + 2359296;   // 1024
        float* dArr2    = ws + 2360320;   // 1024
        float* hid2     = ws + 2361344;   // 16384
        float* gen2     = ws + 2377728;   // 8192
        float* pvals2   = ws + 2385920;   // 131072
        float* pbase2   = ws + 2516992;   // 1024

        k_sctx_x16<<<gs, 256, 0, stream>>>(u_enc, Bs, attn_v, hW, partial2, mArr2, dArr2);
        k_ffnn_x32<<<BB, 1024, 0, stream>>>(partial, mArr, dArr, embed, last_hidden,
                                            Whid, bhid, Wout, bout, fidx,
                                            hid2, gen2, pvals2, pbase2);
    }
}

// Round 13
// 65.651 us; speedup vs baseline: 19.2969x; 19.2969x over previous
//
#include <hip/hip_runtime.h>
#include <hip/hip_bf16.h>

#define BB 64
#define TT 512
#define HH 256
#define EE 128
#define VV 32000
#define SS 128
#define LL 16

typedef __attribute__((ext_vector_type(8))) short bf16x8;
typedef __attribute__((ext_vector_type(4))) float f32x4;

static __device__ __forceinline__ unsigned short f2bf(float x) {
    unsigned int u = __float_as_uint(x);
    unsigned int r = (u + 0x7fffu + ((u >> 16) & 1u)) >> 16;
    return (unsigned short)r;
}

// tanh(x) = 1 - 2/(exp2(x*2*log2e)+1)
static __device__ __forceinline__ float ftanh(float x) {
    float y = __builtin_amdgcn_exp2f(x * 2.885390082f);
    return 1.f - 2.f * __builtin_amdgcn_rcpf(y + 1.f);
}

// ================= K1: {hW, prep_b, embed, slot-firstidx} by blockIdx =================
__global__ __launch_bounds__(256) void k_pre(const float* __restrict__ last_hidden,
                                             const float* __restrict__ attn_W,
                                             const float* __restrict__ attn_b,
                                             const int* __restrict__ z_tm1,
                                             const float* __restrict__ emb_W,
                                             const float* __restrict__ ctrl_W,
                                             const float* __restrict__ ctrl_b,
                                             const int* __restrict__ slot,
                                             float* __restrict__ hW,
                                             float* __restrict__ embed,
                                             unsigned short* __restrict__ Bs,
                                             int* __restrict__ fidx) {
    __shared__ float sh[HH];
    __shared__ int shi[256];
    int blk = blockIdx.x;
    int tid = threadIdx.x;
    if (blk < 64) {
        int b = blk, h = tid;
        sh[h] = last_hidden[b * HH + h];
        __syncthreads();
        const float4* wrow = (const float4*)(attn_W + (size_t)h * (2 * HH));
        float a0 = 0.f, a1 = 0.f, a2 = 0.f, a3 = 0.f;
        for (int k4 = 0; k4 < HH / 4; k4 += 4) {
            float4 w0 = wrow[k4], w1 = wrow[k4+1], w2 = wrow[k4+2], w3 = wrow[k4+3];
            a0 += sh[k4*4+ 0]*w0.x + sh[k4*4+ 1]*w0.y + sh[k4*4+ 2]*w0.z + sh[k4*4+ 3]*w0.w;
            a1 += sh[k4*4+ 4]*w1.x + sh[k4*4+ 5]*w1.y + sh[k4*4+ 6]*w1.z + sh[k4*4+ 7]*w1.w;
            a2 += sh[k4*4+ 8]*w2.x + sh[k4*4+ 9]*w2.y + sh[k4*4+10]*w2.z + sh[k4*4+11]*w2.w;
            a3 += sh[k4*4+12]*w3.x + sh[k4*4+13]*w3.y + sh[k4*4+14]*w3.z + sh[k4*4+15]*w3.w;
        }
        hW[b * HH + h] = attn_b[h] + ((a0 + a1) + (a2 + a3));
    } else if (blk < 96) {
        // Bs layout: [kstep 0..7][tile 0..15][lane 0..63][8 bf16]
        int idx = (blk - 64) * 256 + tid;  // 8192 total
        int lane = idx & 63;
        int gt = (idx >> 6) & 15;
        int ks = idx >> 10;
        int col = gt * 16 + (lane & 15);
        int k0 = ks * 32 + (lane >> 4) * 8;
        const float* src = attn_W + (size_t)col * (2 * HH) + HH + k0;
        unsigned int p0 = f2bf(src[0]) | ((unsigned int)f2bf(src[1]) << 16);
        unsigned int p1 = f2bf(src[2]) | ((unsigned int)f2bf(src[3]) << 16);
        unsigned int p2 = f2bf(src[4]) | ((unsigned int)f2bf(src[5]) << 16);
        unsigned int p3 = f2bf(src[6]) | ((unsigned int)f2bf(src[7]) << 16);
        *(uint4*)(Bs + (size_t)idx * 8) = make_uint4(p0, p1, p2, p3);
    } else if (blk < 160) {
        int b = blk - 96;
        if (tid < EE) sh[tid] = emb_W[(size_t)z_tm1[b] * EE + tid];
        __syncthreads();
        if (tid < EE) {
            const float4* wrow = (const float4*)(ctrl_W + (size_t)tid * EE);
            float a0 = 0.f, a1 = 0.f;
            for (int k4 = 0; k4 < EE / 4; k4 += 2) {
                float4 w0 = wrow[k4], w1 = wrow[k4+1];
                a0 += sh[k4*4+0]*w0.x + sh[k4*4+1]*w0.y + sh[k4*4+2]*w0.z + sh[k4*4+3]*w0.w;
                a1 += sh[k4*4+4]*w1.x + sh[k4*4+5]*w1.y + sh[k4*4+6]*w1.z + sh[k4*4+7]*w1.w;
            }
            embed[b * EE + tid] = ctrl_b[tid] + sh[tid] + a0 + a1;
        }
    } else {
        // blocks 160..167: firstidx[l][s]
        int lblk = (blk - 160) * 2;
        shi[tid] = slot[lblk * SS + tid];
        __syncthreads();
        int lrow = tid >> 7, s = tid & 127;
        int c = shi[lrow * 128 + s];
        int fi = s;
        for (int s2 = 0; s2 < 128; ++s2) {
            if (shi[lrow * 128 + s2] == c) { fi = s2; break; }
        }
        fidx[(lblk + lrow) * SS + s] = fi;
    }
}

// ================= K2: fused scores+context (flash-style), block=(c,b) =================
__global__ __launch_bounds__(256) void k_sctx(const float* __restrict__ enc,
                                              const unsigned short* __restrict__ Bs,
                                              const float* __restrict__ attn_v,
                                              const float* __restrict__ hW,
                                              float* __restrict__ partial,
                                              float* __restrict__ mArr,
                                              float* __restrict__ dArr) {
    __shared__ uint4 AbufV[1024];
    __shared__ float scpart[128];
    __shared__ float wloc[32];
    __shared__ __align__(16) float part[1024];
    unsigned char* Abuf = (unsigned char*)AbufV;

    int c = blockIdx.x, b = blockIdx.y;
    int tid = threadIdx.x;
    int t0 = c * 32;

#pragma unroll
    for (int it = 0; it < 4; ++it) {
        int ci = tid + it * 256;
        int row = ci >> 5;
        int kc = ci & 31;
        const float* src = enc + ((size_t)(t0 + row) * BB + b) * HH + kc * 8;
        float4 f0 = *(const float4*)src;
        float4 f1 = *(const float4*)(src + 4);
        unsigned int p0 = f2bf(f0.x) | ((unsigned int)f2bf(f0.y) << 16);
        unsigned int p1 = f2bf(f0.z) | ((unsigned int)f2bf(f0.w) << 16);
        unsigned int p2 = f2bf(f1.x) | ((unsigned int)f2bf(f1.y) << 16);
        unsigned int p3 = f2bf(f1.z) | ((unsigned int)f2bf(f1.w) << 16);
        int addr = (row * 512 + kc * 16) ^ ((row & 7) << 4);
        *(uint4*)(Abuf + addr) = make_uint4(p0, p1, p2, p3);
    }
    __syncthreads();

    int wv = tid >> 6, lane = tid & 63;
    int lrow = lane & 15, q = lane >> 4;

    f32x4 acc[2][4];
#pragma unroll
    for (int rt = 0; rt < 2; ++rt)
#pragma unroll
        for (int ct = 0; ct < 4; ++ct) acc[rt][ct] = (f32x4){0.f, 0.f, 0.f, 0.f};

    const bf16x8* BsV = (const bf16x8*)Bs;
    for (int ks = 0; ks < 8; ++ks) {
        bf16x8 bfr[4];
        const bf16x8* bsrc = BsV + ((size_t)(ks * 16 + wv * 4) * 64 + lane);
#pragma unroll
        for (int ct = 0; ct < 4; ++ct) bfr[ct] = bsrc[ct * 64];
        bf16x8 afr[2];
#pragma unroll
        for (int rt = 0; rt < 2; ++rt) {
            int arow = rt * 16 + lrow;
            int abyte = (arow * 512 + ks * 64 + q * 16) ^ ((arow & 7) << 4);
            afr[rt] = *(const bf16x8*)(Abuf + abyte);
        }
#pragma unroll
        for (int rt = 0; rt < 2; ++rt)
#pragma unroll
            for (int ct = 0; ct < 4; ++ct)
                acc[rt][ct] = __builtin_amdgcn_mfma_f32_16x16x32_bf16(afr[rt], bfr[ct], acc[rt][ct], 0, 0, 0);
    }

    float vvv[4], hwv[4];
#pragma unroll
    for (int ct = 0; ct < 4; ++ct) {
        int col = wv * 64 + ct * 16 + lrow;
        vvv[ct] = attn_v[col];
        hwv[ct] = hW[(size_t)b * HH + col];
    }
#pragma unroll
    for (int rt = 0; rt < 2; ++rt) {
        float ps[4];
#pragma unroll
        for (int r = 0; r < 4; ++r) {
            float s = 0.f;
#pragma unroll
            for (int ct = 0; ct < 4; ++ct)
                s += vvv[ct] * ftanh(acc[rt][ct][r] + hwv[ct]);
#pragma unroll
            for (int off = 1; off < 16; off <<= 1) s += __shfl_xor(s, off, 64);
            ps[r] = s;
        }
        if (lrow == 0) {
#pragma unroll
            for (int r = 0; r < 4; ++r) scpart[wv * 32 + rt * 16 + q * 4 + r] = ps[r];
        }
    }
    __syncthreads();

    if (tid < 64) {
        float s = (tid < 32)
            ? ((scpart[tid] + scpart[32 + tid]) + (scpart[64 + tid] + scpart[96 + tid]))
            : -3.0e38f;
        float mx = s;
#pragma unroll
        for (int off = 32; off; off >>= 1) mx = fmaxf(mx, __shfl_xor(mx, off, 64));
        float e = (tid < 32) ? expf(s - mx) : 0.f;
        float d = e;
#pragma unroll
        for (int off = 32; off; off >>= 1) d += __shfl_xor(d, off, 64);
        if (tid < 32) wloc[tid] = e;
        if (tid == 0) { mArr[b * 16 + c] = mx; dArr[b * 16 + c] = d; }
    }
    __syncthreads();

    {
        int h4 = tid & 63, g = tid >> 6;
        f32x4 c4 = {0.f, 0.f, 0.f, 0.f};
        f32x4 d4 = {0.f, 0.f, 0.f, 0.f};
        const f32x4* enc4 = (const f32x4*)enc;
        size_t base = ((size_t)(t0 + g * 8) * BB + b) * 64 + h4;
#pragma unroll
        for (int i = 0; i < 8; i += 2) {
            float w0 = wloc[g * 8 + i], w1 = wloc[g * 8 + i + 1];
            f32x4 v0 = enc4[base + (size_t)i * BB * 64];
            f32x4 v1 = enc4[base + (size_t)(i + 1) * BB * 64];
            c4.x += w0 * v0.x; c4.y += w0 * v0.y; c4.z += w0 * v0.z; c4.w += w0 * v0.w;
            d4.x += w1 * v1.x; d4.y += w1 * v1.y; d4.z += w1 * v1.z; d4.w += w1 * v1.w;
        }
        c4.x += d4.x; c4.y += d4.y; c4.z += d4.z; c4.w += d4.w;
        *(f32x4*)&part[g * 256 + h4 * 4] = c4;
    }
    __syncthreads();
    if (tid < 64) {
        f32x4 a0 = *(const f32x4*)&part[0 * 256 + tid * 4];
        f32x4 a1 = *(const f32x4*)&part[1 * 256 + tid * 4];
        f32x4 a2 = *(const f32x4*)&part[2 * 256 + tid * 4];
        f32x4 a3 = *(const f32x4*)&part[3 * 256 + tid * 4];
        f32x4 t4;
        t4.x = (a0.x + a1.x) + (a2.x + a3.x);
        t4.y = (a0.y + a1.y) + (a2.y + a3.y);
        t4.z = (a0.z + a1.z) + (a2.z + a3.z);
        t4.w = (a0.w + a1.w) + (a2.w + a3.w);
        *(f32x4*)&partial[((size_t)c * BB + b) * HH + tid * 4] = t4;
    }
}

// ================= K3: fin[b][640] = [embed | ctx-combined | last_hidden] =================
__global__ __launch_bounds__(256) void k_fin(const float* __restrict__ partial,
                                             const float* __restrict__ mArr,
                                             const float* __restrict__ dArr,
                                             const float* __restrict__ embed,
                                             const float* __restrict__ last_hidden,
                                             float* __restrict__ fin) {
    __shared__ float ldm[16], ldd[16];
    int b = blockIdx.x, tid = threadIdx.x;
    if (tid < 16) { ldm[tid] = mArr[b * 16 + tid]; ldd[tid] = dArr[b * 16 + tid]; }
    __syncthreads();
    float M = ldm[0];
#pragma unroll
    for (int c = 1; c < 16; ++c) M = fmaxf(M, ldm[c]);
    float den = 0.f;
#pragma unroll
    for (int c = 0; c < 16; ++c) den += expf(ldm[c] - M) * ldd[c];
    float invden = 1.f / den;
    float esc[16];
#pragma unroll
    for (int c = 0; c < 16; ++c) esc[c] = expf(ldm[c] - M) * invden;

    for (int j = tid; j < 2 * HH + EE; j += 256) {
        float v;
        if (j < EE) v = embed[b * EE + j];
        else if (j < EE + HH) {
            int h = j - EE;
            float a0 = 0.f, a1 = 0.f;
#pragma unroll
            for (int c = 0; c < 16; c += 2) {
                a0 += esc[c]     * partial[(size_t)c * BB * HH + b * HH + h];
                a1 += esc[c + 1] * partial[(size_t)(c + 1) * BB * HH + b * HH + h];
            }
            v = a0 + a1;
        } else v = last_hidden[b * HH + (j - EE - HH)];
        fin[b * 640 + j] = v;
    }
}

// ================= K4: hidden partial GEMM, 256 blocks (og 32 x kg 8) =================
// paccum[kg][b][o] = sum_{k in kg chunk} fin[b][k] * Whid[o][k]
__global__ __launch_bounds__(256) void k_hid(const float* __restrict__ fin,
                                             const float* __restrict__ Whid,
                                             float* __restrict__ paccum) {
    __shared__ __align__(16) float W_sl[8 * 80];
    __shared__ float fin_sl[64 * 81];
    int og = blockIdx.x >> 3, kg = blockIdx.x & 7;
    int tid = threadIdx.x;
    int k0 = kg * 80, o0 = og * 8;

    for (int i = tid; i < 8 * 80; i += 256) {
        int o = i / 80, kk = i - o * 80;
        W_sl[i] = Whid[(size_t)(o0 + o) * 640 + k0 + kk];
    }
    {
        int b = tid & 63, kc = tid >> 6;
#pragma unroll
        for (int j = 0; j < 20; ++j) {
            int kk = kc * 20 + j;
            fin_sl[b * 81 + kk] = fin[b * 640 + k0 + kk];
        }
    }
    __syncthreads();

    int b = tid & 63, g = tid >> 6;   // g = wave id; o' = g*2, g*2+1
    float a0 = 0.f, a1 = 0.f;
    for (int kk = 0; kk < 80; kk += 4) {
        f32x4 w0 = *(const f32x4*)&W_sl[(g * 2) * 80 + kk];
        f32x4 w1 = *(const f32x4*)&W_sl[(g * 2 + 1) * 80 + kk];
        float f0 = fin_sl[b * 81 + kk + 0];
        float f1 = fin_sl[b * 81 + kk + 1];
        float f2 = fin_sl[b * 81 + kk + 2];
        float f3 = fin_sl[b * 81 + kk + 3];
        a0 += f0 * w0.x + f1 * w0.y + f2 * w0.z + f3 * w0.w;
        a1 += f0 * w1.x + f1 * w1.y + f2 * w1.z + f3 * w1.w;
    }
    paccum[kg * 16384 + b * 256 + o0 + g * 2 + 0] = a0;
    paccum[kg * 16384 + b * 256 + o0 + g * 2 + 1] = a1;
}

// ================= K5: gen GEMM + out_hidden, 256 blocks (sg 32 x bh 8) =================
__global__ __launch_bounds__(256) void k_gensum(const float* __restrict__ paccum,
                                                const float* __restrict__ bhid,
                                                const float* __restrict__ Wout,
                                                const float* __restrict__ bout,
                                                float* __restrict__ out_hidden,
                                                float* __restrict__ gen) {
    __shared__ __align__(16) float WoutL[4 * 256];
    __shared__ float hid_ld[8 * 257];
    __shared__ float boutL[4];
    int sg = blockIdx.x >> 3, bh = blockIdx.x & 7;
    int tid = threadIdx.x;
    int b0 = bh * 8;

    for (int i = tid; i < 4 * 256; i += 256)
        WoutL[i] = Wout[(size_t)(sg * 4 + (i >> 8)) * HH + (i & 255)];
    if (tid < 4) boutL[tid] = bout[sg * 4 + tid];

#pragma unroll
    for (int it = 0; it < 8; ++it) {
        int bidx = (b0 + it) * 256 + tid;
        float v = ((paccum[0 * 16384 + bidx] + paccum[1 * 16384 + bidx])
                 + (paccum[2 * 16384 + bidx] + paccum[3 * 16384 + bidx]))
                + ((paccum[4 * 16384 + bidx] + paccum[5 * 16384 + bidx])
                 + (paccum[6 * 16384 + bidx] + paccum[7 * 16384 + bidx]))
                + bhid[tid];
        hid_ld[it * 257 + tid] = fmaxf(v, 0.f);
    }
    __syncthreads();

    if (sg == 0) {
#pragma unroll
        for (int it = 0; it < 8; ++it)
            out_hidden[(size_t)(b0 + it) * HH + tid] = hid_ld[it * 257 + tid];
    }

    // dot: thread = (oi = tid>>3, kt = tid&7); oi -> (sq = oi>>3, bq = oi&7)
    {
        int oi = tid >> 3, kt = tid & 7;
        int sq = oi >> 3, bq = oi & 7;
        float acc = 0.f;
#pragma unroll 8
        for (int jj = 0; jj < 32; ++jj) {
            int k = kt * 32 + ((jj + 4 * kt) & 31);
            acc += hid_ld[bq * 257 + k] * WoutL[sq * 256 + k];
        }
        acc += __shfl_xor(acc, 1, 64);
        acc += __shfl_xor(acc, 2, 64);
        acc += __shfl_xor(acc, 4, 64);
        if (kt == 0)
            gen[(size_t)(b0 + bq) * SS + sg * 4 + sq] = fmaxf(acc + boutL[sq], 0.f);
    }
}

// ================= K6: probas stats (inline) + streaming fill + scatter =================
__global__ __launch_bounds__(256) void k_fill(const int* __restrict__ slot,
                                              const int* __restrict__ fidx,
                                              const float* __restrict__ gen,
                                              float* __restrict__ out) {
    __shared__ float genl[SS], genacc[SS], pv[SS];
    __shared__ float red[12];
    __shared__ int fidxL[SS], cls[SS];
    int bx = blockIdx.x;
    int row = bx >> 1, half = bx & 1;
    int l = row >> 6, b = row & 63;
    int tid = threadIdx.x;
    int lane = tid & 63, wv = tid >> 6;

    if (tid < SS) {
        genl[tid] = gen[(size_t)b * SS + tid];
        fidxL[tid] = fidx[l * SS + tid];
        cls[tid] = slot[l * SS + tid];
        genacc[tid] = 0.f;
    }
    __syncthreads();
    if (tid < SS) atomicAdd(&genacc[fidxL[tid]], genl[tid]);
    __syncthreads();

    float mg = 0.f;
    bool first = false;
    if (tid < SS) {
        first = (fidxL[tid] == tid);
        mg = -0.01f + genacc[tid];
    }
    float mx = first ? mg : -3.0e38f;
#pragma unroll
    for (int off = 32; off; off >>= 1) mx = fmaxf(mx, __shfl_xor(mx, off, 64));
    if (lane == 0) red[wv] = mx;
    __syncthreads();
    float M = fmaxf(red[0], red[1]);
    float e = first ? expf(mg - M) : 0.f;
    float s1 = e, s2 = first ? 1.f : 0.f;
#pragma unroll
    for (int off = 32; off; off >>= 1) {
        s1 += __shfl_xor(s1, off, 64);
        s2 += __shfl_xor(s2, off, 64);
    }
    if (lane == 0) { red[4 + wv] = s1; red[8 + wv] = s2; }
    __syncthreads();
    float sumHits = red[4] + red[5];
    float cntv = red[8] + red[9];
    float base = expf(-0.01f - M);
    float inv = 1.f / (((float)VV - cntv) * base + sumHits);
    float pb = base * inv;
    if (tid < SS) pv[tid] = first ? e * inv : -1.f;
    __syncthreads();

    float* rowp = out + BB * HH + ((size_t)(l * BB + b)) * VV;
    float4 p4 = make_float4(pb, pb, pb, pb);
    float4* row4 = (float4*)rowp + half * (VV / 8);
#pragma unroll 4
    for (int idx = tid; idx < VV / 8; idx += 256) row4[idx] = p4;
    __syncthreads();
    if (tid < SS && pv[tid] >= 0.f) {
        int c = cls[tid];
        int lo = half * (VV / 2);
        if (c >= lo && c < lo + VV / 2) rowp[c] = pv[tid];
    }
}

extern "C" void kernel_launch(void* const* d_in, const int* in_sizes, int n_in,
                              void* d_out, int out_size, void* d_ws, size_t ws_size,
                              hipStream_t stream) {
    const float* u_enc       = (const float*)d_in[0];
    const float* last_hidden = (const float*)d_in[1];
    const int*   z_tm1       = (const int*)d_in[2];
    const int*   slot        = (const int*)d_in[3];
    const float* emb_W       = (const float*)d_in[4];
    const float* ctrl_W      = (const float*)d_in[5];
    const float* ctrl_b      = (const float*)d_in[6];
    const float* attn_W      = (const float*)d_in[7];
    const float* attn_b      = (const float*)d_in[8];
    const float* attn_v      = (const float*)d_in[9];
    const float* Whid        = (const float*)d_in[10];
    const float* bhid        = (const float*)d_in[11];
    const float* Wout        = (const float*)d_in[12];
    const float* bout        = (const float*)d_in[13];
    float* out = (float*)d_out;
    float* ws = (float*)d_ws;

    float* mArr    = ws;              // 1024
    float* dArr    = ws + 1024;       // 1024
    float* hW      = ws + 32768;      // 16384
    float* embed   = ws + 49152;      // 8192
    float* gen     = ws + 57344;      // 8192
    unsigned short* Bs = (unsigned short*)(ws + 65536);  // 65536 bf16 = 32768 floats
    float* partial = ws + 98304;      // 262144
    float* fin     = ws + 360448;     // 40960
    float* paccum  = ws + 401408;     // 131072
    int*   fidx    = (int*)(ws + 532480);  // 2048 ints

    k_pre<<<168, 256, 0, stream>>>(last_hidden, attn_W, attn_b, z_tm1, emb_W, ctrl_W,
                                   ctrl_b, slot, hW, embed, Bs, fidx);
    dim3 gs(16, BB);
    k_sctx<<<gs, 256, 0, stream>>>(u_enc, Bs, attn_v, hW, partial, mArr, dArr);
    k_fin<<<BB, 256, 0, stream>>>(partial, mArr, dArr, embed, last_hidden, fin);
    k_hid<<<256, 256, 0, stream>>>(fin, Whid, paccum);
    k_gensum<<<256, 256, 0, stream>>>(paccum, bhid, Wout, bout, out, gen);
    k_fill<<<LL * BB * 2, 256, 0, stream>>>(slot, fidx, gen, out);
}

// Round 14
// 64.155 us; speedup vs baseline: 19.7469x; 1.0233x over previous
//
#include <hip/hip_runtime.h>
#include <hip/hip_bf16.h>

#define BB 64
#define TT 512
#define HH 256
#define EE 128
#define VV 32000
#define SS 128
#define LL 16

typedef __attribute__((ext_vector_type(8))) short bf16x8;
typedef __attribute__((ext_vector_type(4))) float f32x4;

static __device__ __forceinline__ unsigned short f2bf(float x) {
    unsigned int u = __float_as_uint(x);
    unsigned int r = (u + 0x7fffu + ((u >> 16) & 1u)) >> 16;
    return (unsigned short)r;
}

// tanh(x) = 1 - 2/(exp2(x*2*log2e)+1)
static __device__ __forceinline__ float ftanh(float x) {
    float y = __builtin_amdgcn_exp2f(x * 2.885390082f);
    return 1.f - 2.f * __builtin_amdgcn_rcpf(y + 1.f);
}

// ================= K1: {hW split-k, prep_b, embed, fidx}, 232 blocks =================
__global__ __launch_bounds__(256) void k_pre(const float* __restrict__ last_hidden,
                                             const float* __restrict__ attn_W,
                                             const float* __restrict__ attn_b,
                                             const int* __restrict__ z_tm1,
                                             const float* __restrict__ emb_W,
                                             const float* __restrict__ ctrl_W,
                                             const float* __restrict__ ctrl_b,
                                             const int* __restrict__ slot,
                                             float* __restrict__ hWp,
                                             float* __restrict__ embed,
                                             unsigned short* __restrict__ Bs,
                                             int* __restrict__ fidx) {
    __shared__ float sh[HH];
    __shared__ int shi[256];
    int blk = blockIdx.x;
    int tid = threadIdx.x;
    if (blk < 128) {
        // hW partial: b = blk>>1, k-half kh = blk&1
        int b = blk >> 1, kh = blk & 1;
        if (tid < 128) sh[tid] = last_hidden[b * HH + kh * 128 + tid];
        __syncthreads();
        const float4* wrow = (const float4*)(attn_W + (size_t)tid * (2 * HH) + kh * 128);
        float a0 = 0.f, a1 = 0.f;
        for (int k4 = 0; k4 < 32; k4 += 2) {
            float4 w0 = wrow[k4], w1 = wrow[k4 + 1];
            a0 += sh[k4*4+0]*w0.x + sh[k4*4+1]*w0.y + sh[k4*4+2]*w0.z + sh[k4*4+3]*w0.w;
            a1 += sh[k4*4+4]*w1.x + sh[k4*4+5]*w1.y + sh[k4*4+6]*w1.z + sh[k4*4+7]*w1.w;
        }
        float r = a0 + a1;
        if (kh == 0) r += attn_b[tid];
        hWp[kh * 16384 + b * 256 + tid] = r;
    } else if (blk < 160) {
        // Bs layout: [kstep 0..7][tile 0..15][lane 0..63][8 bf16]
        int idx = (blk - 128) * 256 + tid;  // 8192 total
        int lane = idx & 63;
        int gt = (idx >> 6) & 15;
        int ks = idx >> 10;
        int col = gt * 16 + (lane & 15);
        int k0 = ks * 32 + (lane >> 4) * 8;
        const float* src = attn_W + (size_t)col * (2 * HH) + HH + k0;
        unsigned int p0 = f2bf(src[0]) | ((unsigned int)f2bf(src[1]) << 16);
        unsigned int p1 = f2bf(src[2]) | ((unsigned int)f2bf(src[3]) << 16);
        unsigned int p2 = f2bf(src[4]) | ((unsigned int)f2bf(src[5]) << 16);
        unsigned int p3 = f2bf(src[6]) | ((unsigned int)f2bf(src[7]) << 16);
        *(uint4*)(Bs + (size_t)idx * 8) = make_uint4(p0, p1, p2, p3);
    } else if (blk < 224) {
        int b = blk - 160;
        if (tid < EE) sh[tid] = emb_W[(size_t)z_tm1[b] * EE + tid];
        __syncthreads();
        if (tid < EE) {
            const float4* wrow = (const float4*)(ctrl_W + (size_t)tid * EE);
            float a0 = 0.f, a1 = 0.f;
            for (int k4 = 0; k4 < EE / 4; k4 += 2) {
                float4 w0 = wrow[k4], w1 = wrow[k4 + 1];
                a0 += sh[k4*4+0]*w0.x + sh[k4*4+1]*w0.y + sh[k4*4+2]*w0.z + sh[k4*4+3]*w0.w;
                a1 += sh[k4*4+4]*w1.x + sh[k4*4+5]*w1.y + sh[k4*4+6]*w1.z + sh[k4*4+7]*w1.w;
            }
            embed[b * EE + tid] = ctrl_b[tid] + sh[tid] + a0 + a1;
        }
    } else {
        // blocks 224..231: firstidx[l][s]
        int lblk = (blk - 224) * 2;
        shi[tid] = slot[lblk * SS + tid];
        __syncthreads();
        int lrow = tid >> 7, s = tid & 127;
        int c = shi[lrow * 128 + s];
        int fi = s;
        for (int s2 = 0; s2 < 128; ++s2) {
            if (shi[lrow * 128 + s2] == c) { fi = s2; break; }
        }
        fidx[(lblk + lrow) * SS + s] = fi;
    }
}

// ================= K2: fused scores+context (flash-style), block=(c,b) =================
// partial layout: [b][c][h]. ctx accumulate reads the bf16 tile from LDS.
__global__ __launch_bounds__(256) void k_sctx(const float* __restrict__ enc,
                                              const unsigned short* __restrict__ Bs,
                                              const float* __restrict__ attn_v,
                                              const float* __restrict__ hWp,
                                              float* __restrict__ partial,
                                              float* __restrict__ mArr,
                                              float* __restrict__ dArr) {
    __shared__ uint4 AbufV[1024];
    __shared__ float scpart[128];
    __shared__ float wloc[32];
    __shared__ __align__(16) float part[1024];
    unsigned char* Abuf = (unsigned char*)AbufV;

    int c = blockIdx.x, b = blockIdx.y;
    int tid = threadIdx.x;
    int t0 = c * 32;

#pragma unroll
    for (int it = 0; it < 4; ++it) {
        int ci = tid + it * 256;
        int row = ci >> 5;
        int kc = ci & 31;
        const float* src = enc + ((size_t)(t0 + row) * BB + b) * HH + kc * 8;
        float4 f0 = *(const float4*)src;
        float4 f1 = *(const float4*)(src + 4);
        unsigned int p0 = f2bf(f0.x) | ((unsigned int)f2bf(f0.y) << 16);
        unsigned int p1 = f2bf(f0.z) | ((unsigned int)f2bf(f0.w) << 16);
        unsigned int p2 = f2bf(f1.x) | ((unsigned int)f2bf(f1.y) << 16);
        unsigned int p3 = f2bf(f1.z) | ((unsigned int)f2bf(f1.w) << 16);
        int addr = (row * 512 + kc * 16) ^ ((row & 7) << 4);
        *(uint4*)(Abuf + addr) = make_uint4(p0, p1, p2, p3);
    }
    __syncthreads();

    int wv = tid >> 6, lane = tid & 63;
    int lrow = lane & 15, q = lane >> 4;

    f32x4 acc[2][4];
#pragma unroll
    for (int rt = 0; rt < 2; ++rt)
#pragma unroll
        for (int ct = 0; ct < 4; ++ct) acc[rt][ct] = (f32x4){0.f, 0.f, 0.f, 0.f};

    const bf16x8* BsV = (const bf16x8*)Bs;
    for (int ks = 0; ks < 8; ++ks) {
        bf16x8 bfr[4];
        const bf16x8* bsrc = BsV + ((size_t)(ks * 16 + wv * 4) * 64 + lane);
#pragma unroll
        for (int ct = 0; ct < 4; ++ct) bfr[ct] = bsrc[ct * 64];
        bf16x8 afr[2];
#pragma unroll
        for (int rt = 0; rt < 2; ++rt) {
            int arow = rt * 16 + lrow;
            int abyte = (arow * 512 + ks * 64 + q * 16) ^ ((arow & 7) << 4);
            afr[rt] = *(const bf16x8*)(Abuf + abyte);
        }
#pragma unroll
        for (int rt = 0; rt < 2; ++rt)
#pragma unroll
            for (int ct = 0; ct < 4; ++ct)
                acc[rt][ct] = __builtin_amdgcn_mfma_f32_16x16x32_bf16(afr[rt], bfr[ct], acc[rt][ct], 0, 0, 0);
    }

    float vvv[4], hwv[4];
#pragma unroll
    for (int ct = 0; ct < 4; ++ct) {
        int col = wv * 64 + ct * 16 + lrow;
        vvv[ct] = attn_v[col];
        hwv[ct] = hWp[(size_t)b * HH + col] + hWp[16384 + (size_t)b * HH + col];
    }
#pragma unroll
    for (int rt = 0; rt < 2; ++rt) {
        float ps[4];
#pragma unroll
        for (int r = 0; r < 4; ++r) {
            float s = 0.f;
#pragma unroll
            for (int ct = 0; ct < 4; ++ct)
                s += vvv[ct] * ftanh(acc[rt][ct][r] + hwv[ct]);
#pragma unroll
            for (int off = 1; off < 16; off <<= 1) s += __shfl_xor(s, off, 64);
            ps[r] = s;
        }
        if (lrow == 0) {
#pragma unroll
            for (int r = 0; r < 4; ++r) scpart[wv * 32 + rt * 16 + q * 4 + r] = ps[r];
        }
    }
    __syncthreads();

    if (tid < 64) {
        float s = (tid < 32)
            ? ((scpart[tid] + scpart[32 + tid]) + (scpart[64 + tid] + scpart[96 + tid]))
            : -3.0e38f;
        float mx = s;
#pragma unroll
        for (int off = 32; off; off >>= 1) mx = fmaxf(mx, __shfl_xor(mx, off, 64));
        float e = (tid < 32) ? expf(s - mx) : 0.f;
        float d = e;
#pragma unroll
        for (int off = 32; off; off >>= 1) d += __shfl_xor(d, off, 64);
        if (tid < 32) wloc[tid] = e;
        if (tid == 0) { mArr[b * 16 + c] = mx; dArr[b * 16 + c] = d; }
    }
    __syncthreads();

    // ctx accumulate from the LDS bf16 tile (no second global pass)
    {
        int h4 = tid & 63, g = tid >> 6;   // wave g covers t rows g*8..g*8+7, full h
        float c0 = 0.f, c1 = 0.f, c2 = 0.f, c3 = 0.f;
#pragma unroll
        for (int i = 0; i < 8; ++i) {
            int row = g * 8 + i;
            float wt = wloc[row];
            int baddr = ((row * 512 + (h4 >> 1) * 16) ^ ((row & 7) << 4)) + (h4 & 1) * 8;
            ushort4 u = *(const ushort4*)(Abuf + baddr);
            c0 += wt * __uint_as_float((unsigned int)u.x << 16);
            c1 += wt * __uint_as_float((unsigned int)u.y << 16);
            c2 += wt * __uint_as_float((unsigned int)u.z << 16);
            c3 += wt * __uint_as_float((unsigned int)u.w << 16);
        }
        part[g * 256 + h4 * 4 + 0] = c0;
        part[g * 256 + h4 * 4 + 1] = c1;
        part[g * 256 + h4 * 4 + 2] = c2;
        part[g * 256 + h4 * 4 + 3] = c3;
    }
    __syncthreads();
    if (tid < 64) {
        f32x4 a0 = *(const f32x4*)&part[0 * 256 + tid * 4];
        f32x4 a1 = *(const f32x4*)&part[1 * 256 + tid * 4];
        f32x4 a2 = *(const f32x4*)&part[2 * 256 + tid * 4];
        f32x4 a3 = *(const f32x4*)&part[3 * 256 + tid * 4];
        f32x4 t4;
        t4.x = (a0.x + a1.x) + (a2.x + a3.x);
        t4.y = (a0.y + a1.y) + (a2.y + a3.y);
        t4.z = (a0.z + a1.z) + (a2.z + a3.z);
        t4.w = (a0.w + a1.w) + (a2.w + a3.w);
        *(f32x4*)&partial[((size_t)b * 16 + c) * HH + tid * 4] = t4;  // [b][c][h]
    }
}

// ================= K3: fin[b][640], 256 blocks (b x quarter) =================
__global__ __launch_bounds__(256) void k_fin(const float* __restrict__ partial,
                                             const float* __restrict__ mArr,
                                             const float* __restrict__ dArr,
                                             const float* __restrict__ embed,
                                             const float* __restrict__ last_hidden,
                                             float* __restrict__ fin) {
    __shared__ float ldm[16], ldd[16];
    int b = blockIdx.x >> 2, qq = blockIdx.x & 3;
    int tid = threadIdx.x;
    if (tid < 16) { ldm[tid] = mArr[b * 16 + tid]; ldd[tid] = dArr[b * 16 + tid]; }
    __syncthreads();
    float M = ldm[0];
#pragma unroll
    for (int c = 1; c < 16; ++c) M = fmaxf(M, ldm[c]);
    float den = 0.f;
#pragma unroll
    for (int c = 0; c < 16; ++c) den += expf(ldm[c] - M) * ldd[c];
    float invden = 1.f / den;

    int j = qq * 160 + tid;
    if (tid < 160) {
        float v;
        if (j < EE) v = embed[b * EE + j];
        else if (j < EE + HH) {
            int h = j - EE;
            const float* pb = partial + (size_t)b * 16 * HH + h;
            float a0 = 0.f, a1 = 0.f;
#pragma unroll
            for (int c = 0; c < 16; c += 2) {
                a0 += expf(ldm[c] - M) * pb[(size_t)c * HH];
                a1 += expf(ldm[c + 1] - M) * pb[(size_t)(c + 1) * HH];
            }
            v = (a0 + a1) * invden;
        } else v = last_hidden[b * HH + (j - EE - HH)];
        fin[b * 640 + j] = v;
    }
}

// ================= K4: hidden partial GEMM, 256 blocks (og 32 x kg 8) =================
__global__ __launch_bounds__(256) void k_hid(const float* __restrict__ fin,
                                             const float* __restrict__ Whid,
                                             float* __restrict__ paccum) {
    __shared__ __align__(16) float W_sl[8 * 80];
    __shared__ float fin_sl[64 * 81];
    int og = blockIdx.x >> 3, kg = blockIdx.x & 7;
    int tid = threadIdx.x;
    int k0 = kg * 80, o0 = og * 8;

    for (int i = tid; i < 8 * 80; i += 256) {
        int o = i / 80, kk = i - o * 80;
        W_sl[i] = Whid[(size_t)(o0 + o) * 640 + k0 + kk];
    }
    {
        int b = tid & 63, kc = tid >> 6;
#pragma unroll
        for (int j = 0; j < 20; ++j) {
            int kk = kc * 20 + j;
            fin_sl[b * 81 + kk] = fin[b * 640 + k0 + kk];
        }
    }
    __syncthreads();

    int b = tid & 63, g = tid >> 6;
    float a0 = 0.f, a1 = 0.f;
    for (int kk = 0; kk < 80; kk += 4) {
        f32x4 w0 = *(const f32x4*)&W_sl[(g * 2) * 80 + kk];
        f32x4 w1 = *(const f32x4*)&W_sl[(g * 2 + 1) * 80 + kk];
        float f0 = fin_sl[b * 81 + kk + 0];
        float f1 = fin_sl[b * 81 + kk + 1];
        float f2 = fin_sl[b * 81 + kk + 2];
        float f3 = fin_sl[b * 81 + kk + 3];
        a0 += f0 * w0.x + f1 * w0.y + f2 * w0.z + f3 * w0.w;
        a1 += f0 * w1.x + f1 * w1.y + f2 * w1.z + f3 * w1.w;
    }
    paccum[kg * 16384 + b * 256 + o0 + g * 2 + 0] = a0;
    paccum[kg * 16384 + b * 256 + o0 + g * 2 + 1] = a1;
}

// ================= K5: gen GEMM + out_hidden, 256 blocks (sg 32 x bh 8) =================
__global__ __launch_bounds__(256) void k_gensum(const float* __restrict__ paccum,
                                                const float* __restrict__ bhid,
                                                const float* __restrict__ Wout,
                                                const float* __restrict__ bout,
                                                float* __restrict__ out_hidden,
                                                float* __restrict__ gen) {
    __shared__ __align__(16) float WoutL[4 * 256];
    __shared__ float hid_ld[8 * 257];
    __shared__ float boutL[4];
    int sg = blockIdx.x >> 3, bh = blockIdx.x & 7;
    int tid = threadIdx.x;
    int b0 = bh * 8;

    for (int i = tid; i < 4 * 256; i += 256)
        WoutL[i] = Wout[(size_t)(sg * 4 + (i >> 8)) * HH + (i & 255)];
    if (tid < 4) boutL[tid] = bout[sg * 4 + tid];

#pragma unroll
    for (int it = 0; it < 8; ++it) {
        int bidx = (b0 + it) * 256 + tid;
        float v = ((paccum[0 * 16384 + bidx] + paccum[1 * 16384 + bidx])
                 + (paccum[2 * 16384 + bidx] + paccum[3 * 16384 + bidx]))
                + ((paccum[4 * 16384 + bidx] + paccum[5 * 16384 + bidx])
                 + (paccum[6 * 16384 + bidx] + paccum[7 * 16384 + bidx]))
                + bhid[tid];
        hid_ld[it * 257 + tid] = fmaxf(v, 0.f);
    }
    __syncthreads();

    if (sg == 0) {
#pragma unroll
        for (int it = 0; it < 8; ++it)
            out_hidden[(size_t)(b0 + it) * HH + tid] = hid_ld[it * 257 + tid];
    }

    {
        int oi = tid >> 3, kt = tid & 7;
        int sq = oi >> 3, bq = oi & 7;
        float acc = 0.f;
#pragma unroll 8
        for (int jj = 0; jj < 32; ++jj) {
            int k = kt * 32 + ((jj + 4 * kt) & 31);
            acc += hid_ld[bq * 257 + k] * WoutL[sq * 256 + k];
        }
        acc += __shfl_xor(acc, 1, 64);
        acc += __shfl_xor(acc, 2, 64);
        acc += __shfl_xor(acc, 4, 64);
        if (kt == 0)
            gen[(size_t)(b0 + bq) * SS + sg * 4 + sq] = fmaxf(acc + boutL[sq], 0.f);
    }
}

// ================= K6: probas stats (inline) + streaming fill + scatter =================
__global__ __launch_bounds__(256) void k_fill(const int* __restrict__ slot,
                                              const int* __restrict__ fidx,
                                              const float* __restrict__ gen,
                                              float* __restrict__ out) {
    __shared__ float genl[SS], genacc[SS], pv[SS];
    __shared__ float red[12];
    __shared__ int fidxL[SS], cls[SS];
    int bx = blockIdx.x;
    int row = bx >> 1, half = bx & 1;
    int l = row >> 6, b = row & 63;
    int tid = threadIdx.x;
    int lane = tid & 63, wv = tid >> 6;

    if (tid < SS) {
        genl[tid] = gen[(size_t)b * SS + tid];
        fidxL[tid] = fidx[l * SS + tid];
        cls[tid] = slot[l * SS + tid];
        genacc[tid] = 0.f;
    }
    __syncthreads();
    if (tid < SS) atomicAdd(&genacc[fidxL[tid]], genl[tid]);
    __syncthreads();

    float mg = 0.f;
    bool first = false;
    if (tid < SS) {
        first = (fidxL[tid] == tid);
        mg = -0.01f + genacc[tid];
    }
    float mx = first ? mg : -3.0e38f;
#pragma unroll
    for (int off = 32; off; off >>= 1) mx = fmaxf(mx, __shfl_xor(mx, off, 64));
    if (lane == 0) red[wv] = mx;
    __syncthreads();
    float M = fmaxf(red[0], red[1]);
    float e = first ? expf(mg - M) : 0.f;
    float s1 = e, s2 = first ? 1.f : 0.f;
#pragma unroll
    for (int off = 32; off; off >>= 1) {
        s1 += __shfl_xor(s1, off, 64);
        s2 += __shfl_xor(s2, off, 64);
    }
    if (lane == 0) { red[4 + wv] = s1; red[8 + wv] = s2; }
    __syncthreads();
    float sumHits = red[4] + red[5];
    float cntv = red[8] + red[9];
    float base = expf(-0.01f - M);
    float inv = 1.f / (((float)VV - cntv) * base + sumHits);
    float pb = base * inv;
    if (tid < SS) pv[tid] = first ? e * inv : -1.f;
    __syncthreads();

    float* rowp = out + BB * HH + ((size_t)(l * BB + b)) * VV;
    float4 p4 = make_float4(pb, pb, pb, pb);
    float4* row4 = (float4*)rowp + half * (VV / 8);
#pragma unroll 4
    for (int idx = tid; idx < VV / 8; idx += 256) row4[idx] = p4;
    __syncthreads();
    if (tid < SS && pv[tid] >= 0.f) {
        int c = cls[tid];
        int lo = half * (VV / 2);
        if (c >= lo && c < lo + VV / 2) rowp[c] = pv[tid];
    }
}

extern "C" void kernel_launch(void* const* d_in, const int* in_sizes, int n_in,
                              void* d_out, int out_size, void* d_ws, size_t ws_size,
                              hipStream_t stream) {
    const float* u_enc       = (const float*)d_in[0];
    const float* last_hidden = (const float*)d_in[1];
    const int*   z_tm1       = (const int*)d_in[2];
    const int*   slot        = (const int*)d_in[3];
    const float* emb_W       = (const float*)d_in[4];
    const float* ctrl_W      = (const float*)d_in[5];
    const float* ctrl_b      = (const float*)d_in[6];
    const float* attn_W      = (const float*)d_in[7];
    const float* attn_b      = (const float*)d_in[8];
    const float* attn_v      = (const float*)d_in[9];
    const float* Whid        = (const float*)d_in[10];
    const float* bhid        = (const float*)d_in[11];
    const float* Wout        = (const float*)d_in[12];
    const float* bout        = (const float*)d_in[13];
    float* out = (float*)d_out;
    float* ws = (float*)d_ws;

    float* mArr    = ws;              // 1024
    float* dArr    = ws + 1024;       // 1024
    float* hWp     = ws + 2048;       // 2*16384 = 32768
    float* embed   = ws + 34816;      // 8192
    float* gen     = ws + 43008;      // 8192
    unsigned short* Bs = (unsigned short*)(ws + 51200);  // 65536 bf16 = 32768 floats
    float* partial = ws + 83968;      // 262144  ([b][c][h])
    float* fin     = ws + 346112;     // 40960
    float* paccum  = ws + 387072;     // 131072
    int*   fidx    = (int*)(ws + 518144);  // 2048 ints

    k_pre<<<232, 256, 0, stream>>>(last_hidden, attn_W, attn_b, z_tm1, emb_W, ctrl_W,
                                   ctrl_b, slot, hWp, embed, Bs, fidx);
    dim3 gs(16, BB);
    k_sctx<<<gs, 256, 0, stream>>>(u_enc, Bs, attn_v, hWp, partial, mArr, dArr);
    k_fin<<<BB * 4, 256, 0, stream>>>(partial, mArr, dArr, embed, last_hidden, fin);
    k_hid<<<256, 256, 0, stream>>>(fin, Whid, paccum);
    k_gensum<<<256, 256, 0, stream>>>(paccum, bhid, Wout, bout, out, gen);
    k_fill<<<LL * BB * 2, 256, 0, stream>>>(slot, fidx, gen, out);
}